// Round 17
// baseline (483.221 us; speedup 1.0000x reference)
//
#include <hip/hip_runtime.h>

#define HD 50
#define TT 512
#define BRR 16        // batch rows per block -> 256 blocks = 1/CU
#define TC 32         // x prefetch chunk (timesteps)
#define KS 136        // shorts per A row (272B): [0..49]=h0 | [50..52]=x | 53..63=0 | [64..113]=h1 | 114..135=0

using f16   = _Float16;
using f16x8 = __attribute__((ext_vector_type(8))) f16;
using f32x4 = __attribute__((ext_vector_type(4))) float;

#define LOG2E 1.4426950408889634f

__device__ __forceinline__ short f2h_bits(float f) {
    f16 h = (f16)f;                      // RNE
    return *reinterpret_cast<short*>(&h);
}
__device__ __forceinline__ float h2f(short b) {
    f16 h = *reinterpret_cast<f16*>(&b);
    return (float)h;
}
__device__ __forceinline__ float frcp(float x) { return __builtin_amdgcn_rcpf(x); }
#if __has_builtin(__builtin_amdgcn_exp2f)
__device__ __forceinline__ float fexp2(float x) { return __builtin_amdgcn_exp2f(x); }
#else
__device__ __forceinline__ float fexp2(float x) { return exp2f(x); }
#endif

// r16 champion + TLP doubling: 1024 threads = 16 waves = 4 waves/SIMD.
// Waves w and w+8 run the SAME MFMA pass (pair p = 8*lr + (w&7); matrix pipe
// was ~idle, duplication is free transport), but split the EW by D-rows:
// wave w applies j=0,1; wave w+8 applies j=2,3. Per-wave trans halves (12
// instrs) -> 4 waves at interleaved phases hide the ds_read->MFMA->exp2 chain.
// Same unified A(n)=[h0|x|h1] one-barrier tick; arithmetic identical to r16
// (absmax must stay exactly 4.882812e-4).
__global__ __launch_bounds__(1024, 4) void lstm2_tlp(
    const float* __restrict__ x,
    const float* __restrict__ Wih0, const float* __restrict__ Whh0,
    const float* __restrict__ bih0, const float* __restrict__ bhh0,
    const float* __restrict__ Wih1, const float* __restrict__ Whh1,
    const float* __restrict__ bih1, const float* __restrict__ bhh1,
    const float* __restrict__ Wfc, const float* __restrict__ bfc,
    float* __restrict__ out)
{
    __shared__ short s_A[2][BRR][KS];
    __shared__ float s_xs[2][BRR][TC * 3];

    const int tid  = threadIdx.x;          // 0..1023
    const int wid  = tid >> 6;             // 0..15
    const int lane = tid & 63;
    const int lr   = lane & 15;            // B/D column = pair slot
    const int lq   = lane >> 4;            // k-octet / D row-quad
    const int r0   = blockIdx.x * BRR;

    const int  wsub = wid & 7;
    const bool jhi  = (wid >= 8);          // false: j=0,1  true: j=2,3
    const int  p     = 8 * lr + wsub;      // pair id 0..127
    const bool valid = (p < 100);
    const bool isL1  = valid && (p >= 50);
    const int  u     = valid ? (isL1 ? p - 50 : p) : 0;
    const int  wcol  = isL1 ? 64 + u : u;  // h write column in A
    const int  rbase = lq * 4 + (jhi ? 2 : 0);   // this wave's 2 D-rows

    // ---- weight B-fragments (f16, pre-scaled), register-resident ----
    f16x8 bw[4][4];
    float bvT[4];
    #pragma unroll
    for (int tt = 0; tt < 4; ++tt) {
        const float sc = (tt == 2) ? (2.0f * LOG2E) : (-LOG2E);
        const int g = tt * HD + u;         // layer-local gate row
        if (!isL1) {
            bvT[tt] = valid ? (bih0[g] + bhh0[g]) * sc : 0.f;
            #pragma unroll
            for (int s = 0; s < 4; ++s) {
                #pragma unroll
                for (int j = 0; j < 8; ++j) {
                    const int k = s*32 + lq*8 + j;
                    float wv = 0.f;
                    if (valid) {
                        if (k < HD) wv = Whh0[g*HD + k];
                        else if (k < HD + 3) wv = Wih0[g*3 + (k - HD)];
                    }
                    bw[tt][s][j] = (f16)(wv * sc);
                }
            }
        } else {
            bvT[tt] = (bih1[g] + bhh1[g]) * sc;
            #pragma unroll
            for (int s = 0; s < 4; ++s) {
                #pragma unroll
                for (int j = 0; j < 8; ++j) {
                    const int k = s*32 + lq*8 + j;
                    float wv = 0.f;
                    if (k < HD) wv = Wih1[g*HD + k];
                    else if (k >= 64 && k < 64 + HD) wv = Whh1[g*HD + (k - 64)];
                    bw[tt][s][j] = (f16)(wv * sc);
                }
            }
        }
    }

    // ---- per-lane c-state: 2 batch rows (rbase, rbase+1) of this (layer,unit) ----
    float cst[2] = {0.f, 0.f};

    // ---- x duty: invalid lanes of waves 0-3 only (jlo group) ----
    const bool xduty = (wid < 4) && (lr >= 13);
    const int  xidx  = wid * 12 + (lr - 13) * 4 + lq;   // 0..47
    const int  xrow  = xidx / 3, xd = xidx % 3;

    // ---- init: zero A buffers, stage x chunk 0, write x(0) ----
    for (int q = tid; q < 2 * BRR * KS; q += 1024) ((short*)s_A)[q] = 0;
    for (int q = tid; q < BRR * TC * 3; q += 1024) {
        const int rr = q / (TC * 3), qq = q % (TC * 3);
        s_xs[0][rr][qq] = x[(size_t)(r0 + rr) * (TT * 3) + qq];
    }
    __syncthreads();
    if (xduty) s_A[0][xrow][HD + xd] = f2h_bits(s_xs[0][xrow][xd]);
    __syncthreads();

    // ================= main loop: TT+1 ticks, ONE barrier each =================
    #pragma unroll 2
    for (int n = 0; n <= TT; ++n) {
        // ---- MFMA: gates for L0(n) and L1(n-1) in one pass ----
        const char* ab = (const char*)&s_A[n & 1][0][0];
        f16x8 a[4];
        #pragma unroll
        for (int s = 0; s < 4; ++s)
            a[s] = *(const f16x8*)(ab + lr * (2 * KS) + s * 64 + lq * 16);
        f32x4 acc[4];
        #pragma unroll
        for (int tt = 0; tt < 4; ++tt) { const float b = bvT[tt]; acc[tt] = (f32x4){b, b, b, b}; }
        #pragma unroll
        for (int s = 0; s < 4; ++s) {
            #pragma unroll
            for (int tt = 0; tt < 4; ++tt)
                acc[tt] = __builtin_amdgcn_mfma_f32_16x16x32_f16(a[s], bw[tt][s], acc[tt], 0, 0, 0);
        }

        // ---- EW for this wave's 2 rows (uniform select, no dynamic vec index) ----
        const bool act = valid && (isL1 ? (n >= 1) : (n < TT));
        if (act) {
            float pre[4][2];
            #pragma unroll
            for (int tt = 0; tt < 4; ++tt) {
                pre[tt][0] = jhi ? acc[tt][2] : acc[tt][0];
                pre[tt][1] = jhi ? acc[tt][3] : acc[tt][1];
            }
            float P[2], num1[2], D1[2], D2[2], eo2[2];
            #pragma unroll
            for (int jj = 0; jj < 2; ++jj) {
                const float ei = fexp2(pre[0][jj]);
                const float ef = fexp2(pre[1][jj]);
                const float eg = fexp2(pre[2][jj]);
                eo2[jj] = fexp2(pre[3][jj]);
                D1[jj] = (eg + 1.0f) * (1.0f + ei);
                D2[jj] = 1.0f + ef;
                P[jj]  = D1[jj] * D2[jj];
                num1[jj] = eg - 1.0f;
            }
            const float rA = frcp(P[0] * P[1]);
            const float iP[2] = { rA * P[1], rA * P[0] };
            float num2[2], den2[2];
            #pragma unroll
            for (int jj = 0; jj < 2; ++jj) {
                const float ig = num1[jj] * (iP[jj] * D2[jj]);   // tanh(g)*sig(i)
                const float fv = iP[jj] * D1[jj];                // sig(f)
                const float c  = fv * cst[jj] + ig;
                cst[jj] = c;
                const float ec = fexp2(c * (2.0f * LOG2E));
                num2[jj] = ec - 1.0f;
                den2[jj] = (ec + 1.0f) * (1.0f + eo2[jj]);
            }
            const float rC = frcp(den2[0] * den2[1]);
            const float iD[2] = { rC * den2[1], rC * den2[0] };
            #pragma unroll
            for (int jj = 0; jj < 2; ++jj)
                s_A[(n + 1) & 1][rbase + jj][wcol] = f2h_bits(num2[jj] * iD[jj]);
        }
        if (xduty && (n + 1) < TT) {                  // x(n+1) from staged LDS
            const int tn = n + 1;
            s_A[(n + 1) & 1][xrow][HD + xd] =
                f2h_bits(s_xs[(tn / TC) & 1][xrow][(tn % TC) * 3 + xd]);
        }
        {
            const int t2s = n + 2;                    // stage next x chunk 2 ticks ahead
            if (t2s < TT && (t2s % TC) == 0) {
                const int cb = (t2s / TC) & 1;
                for (int q = tid; q < BRR * TC * 3; q += 1024) {
                    const int rr = q / (TC * 3), qq = q % (TC * 3);
                    s_xs[cb][rr][qq] = x[(size_t)(r0 + rr) * (TT * 3) + (size_t)t2s * 3 + qq];
                }
            }
        }
        __syncthreads();
    }

    // ---- FC epilogue: h1(TT-1) sits in buf[(TT+1)&1] = buf[1], cols 64..113 ----
    if (tid < BRR * 7) {
        const int r = tid / 7, o = tid % 7;
        float acc = bfc[o];
        #pragma unroll
        for (int uu = 0; uu < HD; ++uu)
            acc += h2f(s_A[1][r][64 + uu]) * Wfc[o * HD + uu];
        out[(size_t)(r0 + r) * 7 + o] = acc;
    }
}

extern "C" void kernel_launch(void* const* d_in, const int* in_sizes, int n_in,
                              void* d_out, int out_size, void* d_ws, size_t ws_size,
                              hipStream_t stream) {
    const float* xp    = (const float*)d_in[0];
    const float* Wih0  = (const float*)d_in[1];
    const float* Whh0  = (const float*)d_in[2];
    const float* bih0  = (const float*)d_in[3];
    const float* bhh0  = (const float*)d_in[4];
    const float* Wih1  = (const float*)d_in[5];
    const float* Whh1  = (const float*)d_in[6];
    const float* bih1  = (const float*)d_in[7];
    const float* bhh1  = (const float*)d_in[8];
    const float* Wfc   = (const float*)d_in[9];
    const float* bfc   = (const float*)d_in[10];
    float* outp = (float*)d_out;

    const int B = in_sizes[0] / (TT * 3);   // 4096
    const int grid = B / BRR;               // 256 blocks, 1 per CU

    lstm2_tlp<<<grid, 1024, 0, stream>>>(
        xp, Wih0, Whh0, bih0, bhh0, Wih1, Whh1, bih1, bhh1, Wfc, bfc, outp);
}

// Round 18
// 414.216 us; speedup vs baseline: 1.1666x; 1.1666x over previous
//
#include <hip/hip_runtime.h>

#define HD 50
#define TT 512
#define BRR 16        // batch rows per block -> 256 blocks = 1/CU
#define TC 32         // x prefetch chunk (timesteps)
#define KS 136        // shorts per A row (272B): [0..49]=h0 | [50..52]=x | 53..63=0 | [64..113]=h1 | 114..135=0

using f16   = _Float16;
using f16x8 = __attribute__((ext_vector_type(8))) f16;
using f32x4 = __attribute__((ext_vector_type(4))) float;

#define LOG2E 1.4426950408889634f

__device__ __forceinline__ short f2h_bits(float f) {
    f16 h = (f16)f;                      // RNE
    return *reinterpret_cast<short*>(&h);
}
__device__ __forceinline__ float h2f(short b) {
    f16 h = *reinterpret_cast<f16*>(&b);
    return (float)h;
}
__device__ __forceinline__ float frcp(float x) { return __builtin_amdgcn_rcpf(x); }
#if __has_builtin(__builtin_amdgcn_exp2f)
__device__ __forceinline__ float fexp2(float x) { return __builtin_amdgcn_exp2f(x); }
#else
__device__ __forceinline__ float fexp2(float x) { return exp2f(x); }
#endif

// r16 champion + MFMA/trans ILP interleave: each gate-tile's 4-MFMA chain is
// immediately followed by its 4 exp2's, so tt=0's trans ops execute (separate
// pipe) while tt=1..3's MFMAs are in flight -> the post-MFMA EW tail shrinks
// from 20 exp2 + chain to 4 exp2 + chain. Arithmetic identical to r16
// (absmax must stay exactly 4.882812e-4).
// A(n) = [h0(n-1)|x(n)|h1(n-2)] (k=128), one MFMA pass for L0(n)+L1(n-1),
// pair p = 8*lr + wid, in-register EW, paired rcp, ONE barrier/tick.
__global__ __launch_bounds__(512, 2) void lstm2_ilp(
    const float* __restrict__ x,
    const float* __restrict__ Wih0, const float* __restrict__ Whh0,
    const float* __restrict__ bih0, const float* __restrict__ bhh0,
    const float* __restrict__ Wih1, const float* __restrict__ Whh1,
    const float* __restrict__ bih1, const float* __restrict__ bhh1,
    const float* __restrict__ Wfc, const float* __restrict__ bfc,
    float* __restrict__ out)
{
    __shared__ short s_A[2][BRR][KS];
    __shared__ float s_xs[2][BRR][TC * 3];

    const int tid  = threadIdx.x;
    const int wid  = tid >> 6;
    const int lane = tid & 63;
    const int lr   = lane & 15;          // B/D column = pair slot
    const int lq   = lane >> 4;          // k-octet / D row-quad
    const int r0   = blockIdx.x * BRR;

    const int  p     = 8 * lr + wid;     // pair id 0..127
    const bool valid = (p < 100);
    const bool isL1  = valid && (p >= 50);
    const int  u     = valid ? (isL1 ? p - 50 : p) : 0;
    const int  wcol  = isL1 ? 64 + u : u;        // h write column in A

    // ---- weight B-fragments (f16, pre-scaled), register-resident ----
    f16x8 bw[4][4];
    float bvT[4];
    #pragma unroll
    for (int tt = 0; tt < 4; ++tt) {
        const float sc = (tt == 2) ? (2.0f * LOG2E) : (-LOG2E);
        const int g = tt * HD + u;       // layer-local gate row
        if (!isL1) {
            bvT[tt] = valid ? (bih0[g] + bhh0[g]) * sc : 0.f;
            #pragma unroll
            for (int s = 0; s < 4; ++s) {
                #pragma unroll
                for (int j = 0; j < 8; ++j) {
                    const int k = s*32 + lq*8 + j;
                    float wv = 0.f;
                    if (valid) {
                        if (k < HD) wv = Whh0[g*HD + k];
                        else if (k < HD + 3) wv = Wih0[g*3 + (k - HD)];
                    }
                    bw[tt][s][j] = (f16)(wv * sc);
                }
            }
        } else {
            bvT[tt] = (bih1[g] + bhh1[g]) * sc;
            #pragma unroll
            for (int s = 0; s < 4; ++s) {
                #pragma unroll
                for (int j = 0; j < 8; ++j) {
                    const int k = s*32 + lq*8 + j;
                    float wv = 0.f;
                    if (k < HD) wv = Wih1[g*HD + k];
                    else if (k >= 64 && k < 64 + HD) wv = Whh1[g*HD + (k - 64)];
                    bw[tt][s][j] = (f16)(wv * sc);
                }
            }
        }
    }

    // ---- per-lane c-state: 4 batch rows (4*lq+j) of this lane's (layer,unit) ----
    float cst[4] = {0.f, 0.f, 0.f, 0.f};

    // ---- x duty: the 48 invalid lanes of waves 0-3 (lr>=13 -> p>=104) ----
    const bool xduty = (wid < 4) && (lr >= 13);
    const int  xidx  = wid * 12 + (lr - 13) * 4 + lq;   // 0..47
    const int  xrow  = xidx / 3, xd = xidx % 3;

    // ---- init: zero A buffers, stage x chunk 0, write x(0) ----
    for (int q = tid; q < 2 * BRR * KS; q += 512) ((short*)s_A)[q] = 0;
    for (int q = tid; q < BRR * TC * 3; q += 512) {
        const int rr = q / (TC * 3), qq = q % (TC * 3);
        s_xs[0][rr][qq] = x[(size_t)(r0 + rr) * (TT * 3) + qq];
    }
    __syncthreads();
    if (xduty) s_A[0][xrow][HD + xd] = f2h_bits(s_xs[0][xrow][xd]);
    __syncthreads();

    // ================= main loop: TT+1 ticks, ONE barrier each =================
    #pragma unroll 2
    for (int n = 0; n <= TT; ++n) {
        // ---- A fragments ----
        const char* ab = (const char*)&s_A[n & 1][0][0];
        f16x8 a[4];
        #pragma unroll
        for (int s = 0; s < 4; ++s)
            a[s] = *(const f16x8*)(ab + lr * (2 * KS) + s * 64 + lq * 16);

        // ---- per-tile MFMA chain immediately followed by its exp2's:
        //      tt's trans ops run on the trans pipe while tt+1's MFMAs issue ----
        float ex[4][4];                         // ex[tt][j] = exp2(gate preact)
        #pragma unroll
        for (int tt = 0; tt < 4; ++tt) {
            const float b = bvT[tt];
            f32x4 ac = (f32x4){b, b, b, b};
            #pragma unroll
            for (int s = 0; s < 4; ++s)
                ac = __builtin_amdgcn_mfma_f32_16x16x32_f16(a[s], bw[tt][s], ac, 0, 0, 0);
            #pragma unroll
            for (int j = 0; j < 4; ++j) ex[tt][j] = fexp2(ac[j]);
        }

        // ---- EW tail (paired rcp) -> h into buf[(n+1)&1] ----
        const bool act = valid && (isL1 ? (n >= 1) : (n < TT));
        if (act) {
            float P[4], num1[4], D1[4], D2[4];
            #pragma unroll
            for (int j = 0; j < 4; ++j) {
                D1[j] = (ex[2][j] + 1.0f) * (1.0f + ex[0][j]);
                D2[j] = 1.0f + ex[1][j];
                P[j]  = D1[j] * D2[j];
                num1[j] = ex[2][j] - 1.0f;
            }
            const float rA = frcp(P[0] * P[1]);
            const float rB = frcp(P[2] * P[3]);
            const float iP[4] = { rA * P[1], rA * P[0], rB * P[3], rB * P[2] };
            float num2[4], den2[4];
            #pragma unroll
            for (int j = 0; j < 4; ++j) {
                const float ig = num1[j] * (iP[j] * D2[j]);   // tanh(g)*sig(i)
                const float fv = iP[j] * D1[j];               // sig(f)
                const float c  = fv * cst[j] + ig;
                cst[j] = c;
                const float ec = fexp2(c * (2.0f * LOG2E));
                num2[j] = ec - 1.0f;
                den2[j] = (ec + 1.0f) * (1.0f + ex[3][j]);
            }
            const float rC = frcp(den2[0] * den2[1]);
            const float rD = frcp(den2[2] * den2[3]);
            const float iD[4] = { rC * den2[1], rC * den2[0], rD * den2[3], rD * den2[2] };
            #pragma unroll
            for (int j = 0; j < 4; ++j)
                s_A[(n + 1) & 1][lq * 4 + j][wcol] = f2h_bits(num2[j] * iD[j]);
        }
        if (xduty && (n + 1) < TT) {                  // x(n+1) from staged LDS
            const int tn = n + 1;
            s_A[(n + 1) & 1][xrow][HD + xd] =
                f2h_bits(s_xs[(tn / TC) & 1][xrow][(tn % TC) * 3 + xd]);
        }
        {
            const int t2s = n + 2;                    // stage next x chunk 2 ticks ahead
            if (t2s < TT && (t2s % TC) == 0) {
                const int cb = (t2s / TC) & 1;
                for (int q = tid; q < BRR * TC * 3; q += 512) {
                    const int rr = q / (TC * 3), qq = q % (TC * 3);
                    s_xs[cb][rr][qq] = x[(size_t)(r0 + rr) * (TT * 3) + (size_t)t2s * 3 + qq];
                }
            }
        }
        __syncthreads();
    }

    // ---- FC epilogue: h1(TT-1) sits in buf[(TT+1)&1] = buf[1], cols 64..113 ----
    if (tid < BRR * 7) {
        const int r = tid / 7, o = tid % 7;
        float acc = bfc[o];
        #pragma unroll
        for (int uu = 0; uu < HD; ++uu)
            acc += h2f(s_A[1][r][64 + uu]) * Wfc[o * HD + uu];
        out[(size_t)(r0 + r) * 7 + o] = acc;
    }
}

extern "C" void kernel_launch(void* const* d_in, const int* in_sizes, int n_in,
                              void* d_out, int out_size, void* d_ws, size_t ws_size,
                              hipStream_t stream) {
    const float* xp    = (const float*)d_in[0];
    const float* Wih0  = (const float*)d_in[1];
    const float* Whh0  = (const float*)d_in[2];
    const float* bih0  = (const float*)d_in[3];
    const float* bhh0  = (const float*)d_in[4];
    const float* Wih1  = (const float*)d_in[5];
    const float* Whh1  = (const float*)d_in[6];
    const float* bih1  = (const float*)d_in[7];
    const float* bhh1  = (const float*)d_in[8];
    const float* Wfc   = (const float*)d_in[9];
    const float* bfc   = (const float*)d_in[10];
    float* outp = (float*)d_out;

    const int B = in_sizes[0] / (TT * 3);   // 4096
    const int grid = B / BRR;               // 256 blocks, 1 per CU

    lstm2_ilp<<<grid, 512, 0, stream>>>(
        xp, Wih0, Whh0, bih0, bhh0, Wih1, Whh1, bih1, bhh1, Wfc, bfc, outp);
}

// Round 19
// 386.184 us; speedup vs baseline: 1.2513x; 1.0726x over previous
//
#include <hip/hip_runtime.h>

#define HD 50
#define TT 512
#define BRR 16        // batch rows per block -> 256 blocks = 1/CU
#define TC 32         // x prefetch chunk (timesteps)
#define KS 136        // shorts per A row (272B): [0..49]=h0 | [50..52]=x | 53..63=0 | [64..113]=h1 | 114..135=0

using f16   = _Float16;
using f16x8 = __attribute__((ext_vector_type(8))) f16;
using f32x4 = __attribute__((ext_vector_type(4))) float;

#define LOG2E 1.4426950408889634f

__device__ __forceinline__ short f2h_bits(float f) {
    f16 h = (f16)f;                      // RNE
    return *reinterpret_cast<short*>(&h);
}
__device__ __forceinline__ float h2f(short b) {
    f16 h = *reinterpret_cast<f16*>(&b);
    return (float)h;
}
__device__ __forceinline__ float frcp(float x) { return __builtin_amdgcn_rcpf(x); }
#if __has_builtin(__builtin_amdgcn_exp2f)
__device__ __forceinline__ float fexp2(float x) { return __builtin_amdgcn_exp2f(x); }
#else
__device__ __forceinline__ float fexp2(float x) { return exp2f(x); }
#endif

// CHAMPION (r16, 386 us): unified one-barrier tick.
// A(n) = [h0(n-1) | x(n) | h1(n-2)] (k=128); one MFMA pass computes L0(n) and
// L1(n-1) gates. Wave w owns (layer,unit) pairs p = 8*lr + w. EW in-register;
// A double-buffered. Weights pre-scaled by -log2e / +2log2e.
// EW: 5 exp2 + 1 shared rcp per j (paired across j: r=rcp(a*b); 1/a=r*b).
// Ledger of rejected variants (measured): 2-barrier stagger -13/-18%,
// 2 blocks/CU -45%, 4 waves/SIMD -25%, source ILP interleave -7%.
__global__ __launch_bounds__(512, 2) void lstm2_uni3(
    const float* __restrict__ x,
    const float* __restrict__ Wih0, const float* __restrict__ Whh0,
    const float* __restrict__ bih0, const float* __restrict__ bhh0,
    const float* __restrict__ Wih1, const float* __restrict__ Whh1,
    const float* __restrict__ bih1, const float* __restrict__ bhh1,
    const float* __restrict__ Wfc, const float* __restrict__ bfc,
    float* __restrict__ out)
{
    __shared__ short s_A[2][BRR][KS];
    __shared__ float s_xs[2][BRR][TC * 3];

    const int tid  = threadIdx.x;
    const int wid  = tid >> 6;
    const int lane = tid & 63;
    const int lr   = lane & 15;          // B/D column = pair slot
    const int lq   = lane >> 4;          // k-octet / D row-quad
    const int r0   = blockIdx.x * BRR;

    const int  p     = 8 * lr + wid;     // pair id 0..127
    const bool valid = (p < 100);
    const bool isL1  = valid && (p >= 50);
    const int  u     = valid ? (isL1 ? p - 50 : p) : 0;
    const int  wcol  = isL1 ? 64 + u : u;        // h write column in A

    // ---- weight B-fragments (f16, pre-scaled), register-resident ----
    f16x8 bw[4][4];
    float bvT[4];
    #pragma unroll
    for (int tt = 0; tt < 4; ++tt) {
        const float sc = (tt == 2) ? (2.0f * LOG2E) : (-LOG2E);
        const int g = tt * HD + u;       // layer-local gate row
        if (!isL1) {
            bvT[tt] = valid ? (bih0[g] + bhh0[g]) * sc : 0.f;
            #pragma unroll
            for (int s = 0; s < 4; ++s) {
                #pragma unroll
                for (int j = 0; j < 8; ++j) {
                    const int k = s*32 + lq*8 + j;
                    float wv = 0.f;
                    if (valid) {
                        if (k < HD) wv = Whh0[g*HD + k];
                        else if (k < HD + 3) wv = Wih0[g*3 + (k - HD)];
                    }
                    bw[tt][s][j] = (f16)(wv * sc);
                }
            }
        } else {
            bvT[tt] = (bih1[g] + bhh1[g]) * sc;
            #pragma unroll
            for (int s = 0; s < 4; ++s) {
                #pragma unroll
                for (int j = 0; j < 8; ++j) {
                    const int k = s*32 + lq*8 + j;
                    float wv = 0.f;
                    if (k < HD) wv = Wih1[g*HD + k];
                    else if (k >= 64 && k < 64 + HD) wv = Whh1[g*HD + (k - 64)];
                    bw[tt][s][j] = (f16)(wv * sc);
                }
            }
        }
    }

    // ---- per-lane c-state: 4 batch rows (4*lq+j) of this lane's (layer,unit) ----
    float cst[4] = {0.f, 0.f, 0.f, 0.f};

    // ---- x duty: the 48 invalid lanes of waves 0-3 (lr>=13 -> p>=104) ----
    const bool xduty = (wid < 4) && (lr >= 13);
    const int  xidx  = wid * 12 + (lr - 13) * 4 + lq;   // 0..47
    const int  xrow  = xidx / 3, xd = xidx % 3;

    // ---- init: zero A buffers, stage x chunk 0, write x(0) ----
    for (int q = tid; q < 2 * BRR * KS; q += 512) ((short*)s_A)[q] = 0;
    for (int q = tid; q < BRR * TC * 3; q += 512) {
        const int rr = q / (TC * 3), qq = q % (TC * 3);
        s_xs[0][rr][qq] = x[(size_t)(r0 + rr) * (TT * 3) + qq];
    }
    __syncthreads();
    if (xduty) s_A[0][xrow][HD + xd] = f2h_bits(s_xs[0][xrow][xd]);
    __syncthreads();

    // ================= main loop: TT+1 ticks, ONE barrier each =================
    #pragma unroll 2
    for (int n = 0; n <= TT; ++n) {
        // ---- MFMA: gates for L0(n) and L1(n-1) in one pass ----
        const char* ab = (const char*)&s_A[n & 1][0][0];
        f16x8 a[4];
        #pragma unroll
        for (int s = 0; s < 4; ++s)
            a[s] = *(const f16x8*)(ab + lr * (2 * KS) + s * 64 + lq * 16);
        f32x4 acc[4];
        #pragma unroll
        for (int tt = 0; tt < 4; ++tt) { const float b = bvT[tt]; acc[tt] = (f32x4){b, b, b, b}; }
        #pragma unroll
        for (int s = 0; s < 4; ++s) {
            #pragma unroll
            for (int tt = 0; tt < 4; ++tt)
                acc[tt] = __builtin_amdgcn_mfma_f32_16x16x32_f16(a[s], bw[tt][s], acc[tt], 0, 0, 0);
        }

        // ---- EW in-register (paired rcp) -> h into buf[(n+1)&1] ----
        const bool act = valid && (isL1 ? (n >= 1) : (n < TT));
        if (act) {
            // pass 1: form stage-1 denominator products P[j] = D1*D2
            float P[4], num1[4], D1[4], D2[4], eo4[4];
            #pragma unroll
            for (int j = 0; j < 4; ++j) {
                const float ei = fexp2(acc[0][j]);
                const float ef = fexp2(acc[1][j]);
                const float eg = fexp2(acc[2][j]);
                eo4[j] = fexp2(acc[3][j]);
                D1[j] = (eg + 1.0f) * (1.0f + ei);
                D2[j] = 1.0f + ef;
                P[j]  = D1[j] * D2[j];
                num1[j] = eg - 1.0f;
            }
            // shared rcp across j-pairs for stage 1
            const float rA = frcp(P[0] * P[1]);
            const float rB = frcp(P[2] * P[3]);
            const float iP[4] = { rA * P[1], rA * P[0], rB * P[3], rB * P[2] };
            // c update + stage-2 denominators
            float num2[4], den2[4];
            #pragma unroll
            for (int j = 0; j < 4; ++j) {
                const float ig = num1[j] * (iP[j] * D2[j]);   // tanh(g)*sig(i)
                const float fv = iP[j] * D1[j];               // sig(f)
                const float c  = fv * cst[j] + ig;
                cst[j] = c;
                const float ec = fexp2(c * (2.0f * LOG2E));
                num2[j] = ec - 1.0f;
                den2[j] = (ec + 1.0f) * (1.0f + eo4[j]);
            }
            // shared rcp across j-pairs for stage 2, write h
            const float rC = frcp(den2[0] * den2[1]);
            const float rD = frcp(den2[2] * den2[3]);
            const float iD[4] = { rC * den2[1], rC * den2[0], rD * den2[3], rD * den2[2] };
            #pragma unroll
            for (int j = 0; j < 4; ++j)
                s_A[(n + 1) & 1][lq * 4 + j][wcol] = f2h_bits(num2[j] * iD[j]);
        }
        if (xduty && (n + 1) < TT) {                  // x(n+1) from staged LDS
            const int tn = n + 1;
            s_A[(n + 1) & 1][xrow][HD + xd] =
                f2h_bits(s_xs[(tn / TC) & 1][xrow][(tn % TC) * 3 + xd]);
        }
        {
            const int t2s = n + 2;                    // stage next x chunk 2 ticks ahead
            if (t2s < TT && (t2s % TC) == 0) {
                const int cb = (t2s / TC) & 1;
                for (int q = tid; q < BRR * TC * 3; q += 512) {
                    const int rr = q / (TC * 3), qq = q % (TC * 3);
                    s_xs[cb][rr][qq] = x[(size_t)(r0 + rr) * (TT * 3) + (size_t)t2s * 3 + qq];
                }
            }
        }
        __syncthreads();
    }

    // ---- FC epilogue: h1(TT-1) sits in buf[(TT+1)&1] = buf[1], cols 64..113 ----
    if (tid < BRR * 7) {
        const int r = tid / 7, o = tid % 7;
        float acc = bfc[o];
        #pragma unroll
        for (int uu = 0; uu < HD; ++uu)
            acc += h2f(s_A[1][r][64 + uu]) * Wfc[o * HD + uu];
        out[(size_t)(r0 + r) * 7 + o] = acc;
    }
}

extern "C" void kernel_launch(void* const* d_in, const int* in_sizes, int n_in,
                              void* d_out, int out_size, void* d_ws, size_t ws_size,
                              hipStream_t stream) {
    const float* xp    = (const float*)d_in[0];
    const float* Wih0  = (const float*)d_in[1];
    const float* Whh0  = (const float*)d_in[2];
    const float* bih0  = (const float*)d_in[3];
    const float* bhh0  = (const float*)d_in[4];
    const float* Wih1  = (const float*)d_in[5];
    const float* Whh1  = (const float*)d_in[6];
    const float* bih1  = (const float*)d_in[7];
    const float* bhh1  = (const float*)d_in[8];
    const float* Wfc   = (const float*)d_in[9];
    const float* bfc   = (const float*)d_in[10];
    float* outp = (float*)d_out;

    const int B = in_sizes[0] / (TT * 3);   // 4096
    const int grid = B / BRR;               // 256 blocks, 1 per CU

    lstm2_uni3<<<grid, 512, 0, stream>>>(
        xp, Wih0, Whh0, bih0, bhh0, Wih1, Whh1, bih1, bhh1, Wfc, bfc, outp);
}

// Round 20
// 376.887 us; speedup vs baseline: 1.2821x; 1.0247x over previous
//
#include <hip/hip_runtime.h>

#define HD 50
#define TT 512
#define BRR 16        // batch rows per block -> 256 blocks = 1/CU
#define TC 32         // x prefetch chunk (timesteps)
#define KS 136        // shorts per A row (272B): [0..49]=h0 | [50..52]=x | 53..63=0 | [64..113]=h1 | 114..135=0

using f16   = _Float16;
using f16x8 = __attribute__((ext_vector_type(8))) f16;
using f32x4 = __attribute__((ext_vector_type(4))) float;
using f32x2 = __attribute__((ext_vector_type(2))) float;

#define LOG2E 1.4426950408889634f

__device__ __forceinline__ short f2h_bits(float f) {
    f16 h = (f16)f;                      // RNE
    return *reinterpret_cast<short*>(&h);
}
__device__ __forceinline__ float h2f(short b) {
    f16 h = *reinterpret_cast<f16*>(&b);
    return (float)h;
}
__device__ __forceinline__ float frcp(float x) { return __builtin_amdgcn_rcpf(x); }
#if __has_builtin(__builtin_amdgcn_exp2f)
__device__ __forceinline__ float fexp2(float x) { return __builtin_amdgcn_exp2f(x); }
#else
__device__ __forceinline__ float fexp2(float x) { return exp2f(x); }
#endif

// r16 champion (unified one-barrier tick) + two micro changes:
//  (a) EW elementwise math on f32x2 vectors (j-pairs) -> v_pk_{mul,add,fma}_f32
//      dual-issue; trans (exp2/rcp) count unchanged.
//  (b) each gate's MFMA chain split into even/odd-s accumulators (depth 4->2)
//      + one vector add, shortening the tick critical path.
// A(n) = [h0(n-1)|x(n)|h1(n-2)] (k=128); one MFMA pass computes L0(n)+L1(n-1);
// pair p = 8*lr + wid; in-register EW; A double-buffered; weights pre-scaled
// by -log2e / +2log2e. Ledger of rejected structural variants: 2-barrier
// stagger -13/-18%, 2 blocks/CU -45%, 4 waves/SIMD -25%, src ILP -7%.
__global__ __launch_bounds__(512, 2) void lstm2_pk(
    const float* __restrict__ x,
    const float* __restrict__ Wih0, const float* __restrict__ Whh0,
    const float* __restrict__ bih0, const float* __restrict__ bhh0,
    const float* __restrict__ Wih1, const float* __restrict__ Whh1,
    const float* __restrict__ bih1, const float* __restrict__ bhh1,
    const float* __restrict__ Wfc, const float* __restrict__ bfc,
    float* __restrict__ out)
{
    __shared__ short s_A[2][BRR][KS];
    __shared__ float s_xs[2][BRR][TC * 3];

    const int tid  = threadIdx.x;
    const int wid  = tid >> 6;
    const int lane = tid & 63;
    const int lr   = lane & 15;          // B/D column = pair slot
    const int lq   = lane >> 4;          // k-octet / D row-quad
    const int r0   = blockIdx.x * BRR;

    const int  p     = 8 * lr + wid;     // pair id 0..127
    const bool valid = (p < 100);
    const bool isL1  = valid && (p >= 50);
    const int  u     = valid ? (isL1 ? p - 50 : p) : 0;
    const int  wcol  = isL1 ? 64 + u : u;        // h write column in A

    // ---- weight B-fragments (f16, pre-scaled), register-resident ----
    f16x8 bw[4][4];
    float bvT[4];
    #pragma unroll
    for (int tt = 0; tt < 4; ++tt) {
        const float sc = (tt == 2) ? (2.0f * LOG2E) : (-LOG2E);
        const int g = tt * HD + u;       // layer-local gate row
        if (!isL1) {
            bvT[tt] = valid ? (bih0[g] + bhh0[g]) * sc : 0.f;
            #pragma unroll
            for (int s = 0; s < 4; ++s) {
                #pragma unroll
                for (int j = 0; j < 8; ++j) {
                    const int k = s*32 + lq*8 + j;
                    float wv = 0.f;
                    if (valid) {
                        if (k < HD) wv = Whh0[g*HD + k];
                        else if (k < HD + 3) wv = Wih0[g*3 + (k - HD)];
                    }
                    bw[tt][s][j] = (f16)(wv * sc);
                }
            }
        } else {
            bvT[tt] = (bih1[g] + bhh1[g]) * sc;
            #pragma unroll
            for (int s = 0; s < 4; ++s) {
                #pragma unroll
                for (int j = 0; j < 8; ++j) {
                    const int k = s*32 + lq*8 + j;
                    float wv = 0.f;
                    if (k < HD) wv = Wih1[g*HD + k];
                    else if (k >= 64 && k < 64 + HD) wv = Whh1[g*HD + (k - 64)];
                    bw[tt][s][j] = (f16)(wv * sc);
                }
            }
        }
    }

    // ---- per-lane c-state: 2 j-pairs (rows 4lq+{0,1} and 4lq+{2,3}) ----
    f32x2 cstp[2] = { (f32x2){0.f, 0.f}, (f32x2){0.f, 0.f} };

    // ---- x duty: the 48 invalid lanes of waves 0-3 (lr>=13 -> p>=104) ----
    const bool xduty = (wid < 4) && (lr >= 13);
    const int  xidx  = wid * 12 + (lr - 13) * 4 + lq;   // 0..47
    const int  xrow  = xidx / 3, xd = xidx % 3;

    // ---- init: zero A buffers, stage x chunk 0, write x(0) ----
    for (int q = tid; q < 2 * BRR * KS; q += 512) ((short*)s_A)[q] = 0;
    for (int q = tid; q < BRR * TC * 3; q += 512) {
        const int rr = q / (TC * 3), qq = q % (TC * 3);
        s_xs[0][rr][qq] = x[(size_t)(r0 + rr) * (TT * 3) + qq];
    }
    __syncthreads();
    if (xduty) s_A[0][xrow][HD + xd] = f2h_bits(s_xs[0][xrow][xd]);
    __syncthreads();

    // ================= main loop: TT+1 ticks, ONE barrier each =================
    #pragma unroll 2
    for (int n = 0; n <= TT; ++n) {
        // ---- MFMA: gates for L0(n) and L1(n-1); even/odd-s split chains ----
        const char* ab = (const char*)&s_A[n & 1][0][0];
        f16x8 a[4];
        #pragma unroll
        for (int s = 0; s < 4; ++s)
            a[s] = *(const f16x8*)(ab + lr * (2 * KS) + s * 64 + lq * 16);
        f32x4 accE[4], accO[4];
        #pragma unroll
        for (int tt = 0; tt < 4; ++tt) {
            const float b = bvT[tt];
            accE[tt] = (f32x4){b, b, b, b};
            accO[tt] = (f32x4){0.f, 0.f, 0.f, 0.f};
        }
        #pragma unroll
        for (int s = 0; s < 4; ++s) {
            if ((s & 1) == 0) {
                #pragma unroll
                for (int tt = 0; tt < 4; ++tt)
                    accE[tt] = __builtin_amdgcn_mfma_f32_16x16x32_f16(a[s], bw[tt][s], accE[tt], 0, 0, 0);
            } else {
                #pragma unroll
                for (int tt = 0; tt < 4; ++tt)
                    accO[tt] = __builtin_amdgcn_mfma_f32_16x16x32_f16(a[s], bw[tt][s], accO[tt], 0, 0, 0);
            }
        }
        f32x4 acc[4];
        #pragma unroll
        for (int tt = 0; tt < 4; ++tt) acc[tt] = accE[tt] + accO[tt];

        // ---- EW on f32x2 packed lanes (j-pairs) -> h into buf[(n+1)&1] ----
        const bool act = valid && (isL1 ? (n >= 1) : (n < TT));
        if (act) {
            f32x2 hv2[2];
            #pragma unroll
            for (int hp = 0; hp < 2; ++hp) {
                const int j0 = 2 * hp, j1 = 2 * hp + 1;
                const f32x2 ei = { fexp2(acc[0][j0]), fexp2(acc[0][j1]) };
                const f32x2 ef = { fexp2(acc[1][j0]), fexp2(acc[1][j1]) };
                const f32x2 eg = { fexp2(acc[2][j0]), fexp2(acc[2][j1]) };
                const f32x2 eo = { fexp2(acc[3][j0]), fexp2(acc[3][j1]) };
                const f32x2 D1 = (eg + 1.0f) * (ei + 1.0f);
                const f32x2 D2 = ef + 1.0f;
                const f32x2 P  = D1 * D2;
                const f32x2 num1 = eg - 1.0f;
                const float r1 = frcp(P.x * P.y);
                const f32x2 iP = r1 * __builtin_shufflevector(P, P, 1, 0);
                const f32x2 ig = num1 * (iP * D2);   // tanh(g)*sig(i)
                const f32x2 fv = iP * D1;            // sig(f)
                const f32x2 c  = fv * cstp[hp] + ig;
                cstp[hp] = c;
                const f32x2 ecarg = c * (2.0f * LOG2E);
                const f32x2 ec = { fexp2(ecarg.x), fexp2(ecarg.y) };
                const f32x2 num2 = ec - 1.0f;
                const f32x2 den2 = (ec + 1.0f) * (eo + 1.0f);
                const float r2 = frcp(den2.x * den2.y);
                const f32x2 iD = r2 * __builtin_shufflevector(den2, den2, 1, 0);
                hv2[hp] = num2 * iD;
            }
            s_A[(n + 1) & 1][lq * 4 + 0][wcol] = f2h_bits(hv2[0].x);
            s_A[(n + 1) & 1][lq * 4 + 1][wcol] = f2h_bits(hv2[0].y);
            s_A[(n + 1) & 1][lq * 4 + 2][wcol] = f2h_bits(hv2[1].x);
            s_A[(n + 1) & 1][lq * 4 + 3][wcol] = f2h_bits(hv2[1].y);
        }
        if (xduty && (n + 1) < TT) {                  // x(n+1) from staged LDS
            const int tn = n + 1;
            s_A[(n + 1) & 1][xrow][HD + xd] =
                f2h_bits(s_xs[(tn / TC) & 1][xrow][(tn % TC) * 3 + xd]);
        }
        {
            const int t2s = n + 2;                    // stage next x chunk 2 ticks ahead
            if (t2s < TT && (t2s % TC) == 0) {
                const int cb = (t2s / TC) & 1;
                for (int q = tid; q < BRR * TC * 3; q += 512) {
                    const int rr = q / (TC * 3), qq = q % (TC * 3);
                    s_xs[cb][rr][qq] = x[(size_t)(r0 + rr) * (TT * 3) + (size_t)t2s * 3 + qq];
                }
            }
        }
        __syncthreads();
    }

    // ---- FC epilogue: h1(TT-1) sits in buf[(TT+1)&1] = buf[1], cols 64..113 ----
    if (tid < BRR * 7) {
        const int r = tid / 7, o = tid % 7;
        float acc = bfc[o];
        #pragma unroll
        for (int uu = 0; uu < HD; ++uu)
            acc += h2f(s_A[1][r][64 + uu]) * Wfc[o * HD + uu];
        out[(size_t)(r0 + r) * 7 + o] = acc;
    }
}

extern "C" void kernel_launch(void* const* d_in, const int* in_sizes, int n_in,
                              void* d_out, int out_size, void* d_ws, size_t ws_size,
                              hipStream_t stream) {
    const float* xp    = (const float*)d_in[0];
    const float* Wih0  = (const float*)d_in[1];
    const float* Whh0  = (const float*)d_in[2];
    const float* bih0  = (const float*)d_in[3];
    const float* bhh0  = (const float*)d_in[4];
    const float* Wih1  = (const float*)d_in[5];
    const float* Whh1  = (const float*)d_in[6];
    const float* bih1  = (const float*)d_in[7];
    const float* bhh1  = (const float*)d_in[8];
    const float* Wfc   = (const float*)d_in[9];
    const float* bfc   = (const float*)d_in[10];
    float* outp = (float*)d_out;

    const int B = in_sizes[0] / (TT * 3);   // 4096
    const int grid = B / BRR;               // 256 blocks, 1 per CU

    lstm2_pk<<<grid, 512, 0, stream>>>(
        xp, Wih0, Whh0, bih0, bhh0, Wih1, Whh1, bih1, bhh1, Wfc, bfc, outp);
}